// Round 4
// baseline (286.789 us; speedup 1.0000x reference)
//
#include <hip/hip_runtime.h>
#include <hip/hip_bf16.h>
#include <stdint.h>

// Problem: out[b,i] = sum_j a_ext[b,j] * W[hash_idx[i,j]]
//   B=4096, FAN_IN=4096 (+1 bias col), FAN_OUT=4096, K-table=65536
// Strategy: bf16 A_ext [B][KP], Wv [FAN_OUT][KP] (K padded 4097->4160),
// then bf16 MFMA GEMM-BT into fp32 C.
// R8: 256x256 8-phase + XOR swizzle: 128us, conflicts 1.7e7->0, Mfma 46%.
// R9: compile-time buffer parity: 118.6us, 1177 TF, Mfma 51.
// R10: build_wv single-pass full-table-LDS gather: total 294->285.
//     Contingency fired: non-gemm residual ~160us barely moved => ~100us is
//     fixed harness overhead + ~50us prep; prep parked.
// R11 (this): gemm lookahead reads. Calibrated model: per tile wall 4580cyc,
//     MFMA need 2480 (54% = measured Mfma 50). ph0's 12 ds_read -> lgkm(0)
//     serial drain + dead boundary vmcnt are the attackable stall. Moves:
//       - tile-boundary wait: ph3-end vmcnt(4) -> ph2-end vmcnt(2). Per-wave
//         FIFO: at ph2-end outstanding = {B0(t+1),A0(t+1),A1(t+1),B1(t+1),
//         B0(t+2)} (10); vmcnt(2) leaves B0(t+2) => ALL of tile t+1 resident.
//       - ph3 pre-reads tile t+1's ph0 operands (12x b128, issued AFTER ph3's
//         lgkm(0)+sched_barrier) from buf[P^1]; consumed at next ph0-mid.
//         Drain window = 16 MFMA + barrier instead of in-phase serial wait.
//     Read distribution 12/4/8/0 -> 0/4/8/12(post-mid). WAR ledger unchanged
//     (pre-reads buf[P^1], ph3 stage writes buf[P]; clamped stages drain at
//     final vmcnt(0)). Prologue pre-reads tile 0; tail uses tile-63 pre-read.

#define B_DIM   4096
#define FAN_IN  4096
#define FAN_OUT 4096
#define KD      (FAN_IN + 1)   // 4097
#define KP      4160           // padded: 65 * 64
#define NKT     65             // K-tiles of BK=64

#define BM 256
#define BN 256
#define BK 64

typedef __attribute__((ext_vector_type(8))) short  short8;   // 8 bf16 = 4 VGPRs
typedef __attribute__((ext_vector_type(4))) float  floatx4;  // MFMA acc

__device__ __forceinline__ unsigned short f2bf(float f) {
  union { float f; unsigned u; } v; v.f = f;
  unsigned u = v.u;
  u += 0x7fffu + ((u >> 16) & 1u);   // round-to-nearest-even
  return (unsigned short)(u >> 16);
}

__device__ __forceinline__ void async16(const void* g, void* l) {
  // direct global->LDS DMA, 16B/lane; LDS dest = wave-uniform base + lane*16
  __builtin_amdgcn_global_load_lds(
      (const __attribute__((address_space(1))) void*)g,
      (__attribute__((address_space(3))) void*)l, 16, 0, 0);
}

// ---- Kernel 1: A_ext[b][j] = bf16(a[b][j]); col 4096 = 1.0; cols 4097..KP-1 = 0
__global__ __launch_bounds__(256) void build_aext(
    const float* __restrict__ a, unsigned short* __restrict__ Ae) {
  const int row = blockIdx.x;
  const float* ar = a + (size_t)row * FAN_IN;
  unsigned short* er = Ae + (size_t)row * KP;
  for (int j4 = threadIdx.x; j4 < KP / 4; j4 += 256) {
    const int j = j4 * 4;
    float x0, x1, x2, x3;
    if (j + 3 < FAN_IN) {
      const float4 v = *(const float4*)(ar + j);   // 16B-aligned (row stride 16KB)
      x0 = v.x; x1 = v.y; x2 = v.z; x3 = v.w;
    } else {
      x0 = (j + 0 < FAN_IN) ? ar[j + 0] : ((j + 0 == FAN_IN) ? 1.0f : 0.0f);
      x1 = (j + 1 < FAN_IN) ? ar[j + 1] : ((j + 1 == FAN_IN) ? 1.0f : 0.0f);
      x2 = (j + 2 < FAN_IN) ? ar[j + 2] : ((j + 2 == FAN_IN) ? 1.0f : 0.0f);
      x3 = (j + 3 < FAN_IN) ? ar[j + 3] : ((j + 3 == FAN_IN) ? 1.0f : 0.0f);
    }
    ushort4 o;
    o.x = f2bf(x0); o.y = f2bf(x1); o.z = f2bf(x2); o.w = f2bf(x3);
    *(ushort4*)(er + j) = o;   // 8B store, aligned
  }
}

// ---- Kernel 2 (R10, measured-kept): Wv[i][j] = bf16(W[hash_idx[i][j]]).
// Single pass: ENTIRE W as bf16 in 128KB dynamic LDS (1 block/CU).
__global__ __launch_bounds__(1024) void build_wv(
    const int* __restrict__ hidx, const float* __restrict__ W,
    unsigned short* __restrict__ Wv) {
  extern __shared__ unsigned short wl[];   // 65536 bf16 = 128 KB
  const int t = threadIdx.x;

  const float4* Wf = (const float4*)W;
#pragma unroll
  for (int i = 0; i < 16; i++) {
    const int f4 = i * 1024 + t;
    const float4 v = Wf[f4];
    ushort4 o;
    o.x = f2bf(v.x); o.y = f2bf(v.y); o.z = f2bf(v.z); o.w = f2bf(v.w);
    *(ushort4*)&wl[f4 * 4] = o;   // byte addr f4*8: 8B aligned, 2-way alias free
  }
  __syncthreads();

  const int r0 = blockIdx.x * 16;
#pragma unroll 4
  for (int r = 0; r < 16; r++) {
    const int* hr = hidx + (size_t)(r0 + r) * KD;
    unsigned short* wr = Wv + (size_t)(r0 + r) * KP;
    const int j = 4 * t;                    // 0..4092: covers cols 0..4095
    ushort4 o;
    o.x = wl[hr[j + 0]];
    o.y = wl[hr[j + 1]];
    o.z = wl[hr[j + 2]];
    o.w = wl[hr[j + 3]];
    *(ushort4*)(wr + j) = o;                // 8B store, aligned (row base 8320B)
    if (t < 64)                             // col 4096 + pad 4097..4159 = 0
      wr[4096 + t] = (t == 0) ? wl[hr[4096]] : (unsigned short)0;
  }
}

// ---- Kernel 3 (R11): 256x256 8-phase GEMM-BT, lookahead operand reads.
// LDS layout (bytes, 128KB dynamic): A: buf*32768 + half*16384 + row*128 + slot*16
//   with physical slot = logical_slot ^ (row&7)  (slot = 16B chunk, 8 per row)
// B region at +65536, same layout.

#define STAGE_A(BUF, H, KOFF)                                                      \
  do {                                                                             \
    async16(pa + ((H) * 128 + 0)  * KP + (KOFF),                                   \
            smb + ((BUF) << 15) + ((H) << 14) + dA);                               \
    async16(pa + ((H) * 128 + 64) * KP + (KOFF),                                   \
            smb + ((BUF) << 15) + ((H) << 14) + 8192 + dA);                        \
  } while (0)

#define STAGE_B(BUF, H, KOFF)                                                      \
  do {                                                                             \
    async16(pb + ((H) * 128 + 0)  * KP + (KOFF),                                   \
            smb + 65536 + ((BUF) << 15) + ((H) << 14) + dA);                       \
    async16(pb + ((H) * 128 + 64) * KP + (KOFF),                                   \
            smb + 65536 + ((BUF) << 15) + ((H) << 14) + 8192 + dA);                \
  } while (0)

#define PHASE_MID()                                                                \
  do {                                                                             \
    asm volatile("" ::: "memory");                                                 \
    __builtin_amdgcn_s_barrier();                                                  \
    asm volatile("s_waitcnt lgkmcnt(0)" ::: "memory");                             \
    __builtin_amdgcn_sched_barrier(0);                                             \
    __builtin_amdgcn_s_setprio(1);                                                 \
  } while (0)

#define PHASE_END()                                                                \
  do {                                                                             \
    __builtin_amdgcn_s_setprio(0);                                                 \
    asm volatile("" ::: "memory");                                                 \
    __builtin_amdgcn_s_barrier();                                                  \
    asm volatile("" ::: "memory");                                                 \
  } while (0)

// tile-boundary wait, moved to ph2-end: all of tile t+1 resident after this
#define PHASE_END_VM2()                                                            \
  do {                                                                             \
    __builtin_amdgcn_s_setprio(0);                                                 \
    asm volatile("s_waitcnt vmcnt(2)" ::: "memory");                               \
    __builtin_amdgcn_s_barrier();                                                  \
    asm volatile("" ::: "memory");                                                 \
  } while (0)

#define MFMA2(ACC, AF, BF)                                                         \
  do {                                                                             \
    ACC = __builtin_amdgcn_mfma_f32_16x16x32_bf16((AF)[0], (BF)[0], ACC, 0, 0, 0); \
    ACC = __builtin_amdgcn_mfma_f32_16x16x32_bf16((AF)[1], (BF)[1], ACC, 0, 0, 0); \
  } while (0)

// One K-tile, compile-time buffer parity P. K1/K2 = element k-offsets of the
// tiles staged this tile (clamped <= 4096). afp[4][2]/bfp[2][2] hold this
// tile's ph0 operands on entry (pre-read during prev ph3 / prologue) and are
// REFILLED during ph3 with tile t+1's ph0 operands from buf[P^1].
#define KTILE(P, K1, K2)                                                           \
  do {                                                                             \
    short8 af[4][2], bf[2][2];                                                     \
    /* ph0: NO ds_reads (operands in afp/bfp); stage A1(t+1) */                    \
    STAGE_A((P) ^ 1, 1, K1);                                                       \
    PHASE_MID();  /* lgkm(0) drains prev-ph3 pre-reads (had full phase+bar) */     \
    _Pragma("unroll")                                                              \
    for (int mi = 0; mi < 4; ++mi)                                                 \
      _Pragma("unroll")                                                            \
      for (int ni = 0; ni < 2; ++ni) MFMA2(acc[mi][ni], afp[mi], bfp[ni]);         \
    PHASE_END();                                                                   \
    /* ph1: read B N2-3 (4 b128); stage B1(t+1); MFMA M0-3 x N2-3 */               \
    _Pragma("unroll")                                                              \
    for (int ni = 0; ni < 2; ++ni) {                                               \
      bf[ni][0] = *(const short8*)(smb + ((P) << 15) + brB + (ni + 2) * 2048 + abase); \
      bf[ni][1] = *(const short8*)(smb + ((P) << 15) + brB + (ni + 2) * 2048 + (abase ^ 64)); \
    }                                                                              \
    STAGE_B((P) ^ 1, 1, K1);                                                       \
    PHASE_MID();                                                                   \
    _Pragma("unroll")                                                              \
    for (int mi = 0; mi < 4; ++mi)                                                 \
      _Pragma("unroll")                                                            \
      for (int ni = 0; ni < 2; ++ni) MFMA2(acc[mi][ni + 2], afp[mi], bf[ni]);      \
    PHASE_END();                                                                   \
    /* ph2: read A M4-7 (8 b128); stage B0(t+2); MFMA M4-7 x N0-1;         */      \
    /* ph2-end vmcnt(2): oldest 8 of {B0,A0,A1,B1}(t+1),B0(t+2) landed ->  */      \
    /* ALL of tile t+1 resident; only B0(t+2) in flight                    */      \
    _Pragma("unroll")                                                              \
    for (int mi = 0; mi < 4; ++mi) {                                               \
      af[mi][0] = *(const short8*)(smb + ((P) << 15) + arB + (mi + 4) * 2048 + abase); \
      af[mi][1] = *(const short8*)(smb + ((P) << 15) + arB + (mi + 4) * 2048 + (abase ^ 64)); \
    }                                                                              \
    STAGE_B((P), 0, K2);                                                           \
    PHASE_MID();                                                                   \
    _Pragma("unroll")                                                              \
    for (int mi = 0; mi < 4; ++mi)                                                 \
      _Pragma("unroll")                                                            \
      for (int ni = 0; ni < 2; ++ni) MFMA2(acc[mi + 4][ni], af[mi], bfp[ni]);      \
    PHASE_END_VM2();                                                               \
    /* ph3: stage A0(t+2); post-mid PRE-READ tile t+1 ph0 ops from buf[P^1] */     \
    /* (12 b128, consumers behind next ph0-mid lgkm+sched_barrier);         */     \
    /* MFMA M4-7 x N2-3. WAR: pre-reads buf[P^1], stage writes buf[P].      */     \
    STAGE_A((P), 0, K2);                                                           \
    PHASE_MID();                                                                   \
    _Pragma("unroll")                                                              \
    for (int mi = 0; mi < 4; ++mi) {                                               \
      afp[mi][0] = *(const short8*)(smb + (((P) ^ 1) << 15) + arB + mi * 2048 + abase); \
      afp[mi][1] = *(const short8*)(smb + (((P) ^ 1) << 15) + arB + mi * 2048 + (abase ^ 64)); \
    }                                                                              \
    _Pragma("unroll")                                                              \
    for (int ni = 0; ni < 2; ++ni) {                                               \
      bfp[ni][0] = *(const short8*)(smb + (((P) ^ 1) << 15) + brB + ni * 2048 + abase); \
      bfp[ni][1] = *(const short8*)(smb + (((P) ^ 1) << 15) + brB + ni * 2048 + (abase ^ 64)); \
    }                                                                              \
    _Pragma("unroll")                                                              \
    for (int mi = 0; mi < 4; ++mi)                                                 \
      _Pragma("unroll")                                                            \
      for (int ni = 0; ni < 2; ++ni) MFMA2(acc[mi + 4][ni + 2], af[mi], bf[ni]);   \
    PHASE_END();  /* no vmcnt at boundary: only {B0,A0}(t+2) in flight */          \
  } while (0)

__global__ __launch_bounds__(512, 2) void gemm_bt8(
    const unsigned short* __restrict__ A, const unsigned short* __restrict__ Bm,
    float* __restrict__ C, int M, int N) {
  extern __shared__ char smb[];   // 128 KB
  const int tid = threadIdx.x;
  const int l   = tid & 63;
  const int w   = tid >> 6;       // 8 waves
  const int wm  = w >> 2;         // 0..1  (M half: rows wm*128..+127)
  const int wn  = w & 3;          // 0..3  (N 64-col strip)
  const int bm  = blockIdx.y * BM;
  const int bn  = blockIdx.x * BN;
  const int q   = l >> 4;         // MFMA k-quad
  const int r   = l & 15;         // MFMA m/n-in-16

  // ---- staging source pointers (pre-swizzled global column) ----
  const int lrow = l >> 3;                       // 0..7 (row-in-8)
  const int lcol = ((l & 7) ^ lrow) * 8;         // swizzled 16B chunk (elements)
  const unsigned short* pa = A  + (size_t)(bm + w * 8 + lrow) * KP + lcol;
  const unsigned short* pb = Bm + (size_t)(bn + w * 8 + lrow) * KP + lcol;
  const int dA = w * 1024;                       // wave's byte base in 8KB slab

  // ---- swizzled ds_read byte offset (within a 16KB half region) ----
  // logical: row = mi*16 + r, slot = ks*4 + q; physical slot ^= (r&7)
  const int abase = r * 128 + ((q ^ (r & 7)) << 4);   // ks=0; ks=1 is ^64
  const int arB   = wm << 14;                         // A half base (sans buf bit)
  const int brB   = 65536 + ((wn >> 1) << 14) + ((wn & 1) << 13);  // B slab base

  floatx4 acc[8][4] = {};
  short8 afp[4][2], bfp[2][2];   // lookahead ph0 operands (persist across tiles)

  // ---- prologue: tile0 -> buf0, then B0(1), A0(1) -> buf1; pre-read tile0 ----
  STAGE_A(0, 0, 0); STAGE_A(0, 1, 0);
  STAGE_B(0, 0, 0); STAGE_B(0, 1, 0);
  STAGE_B(1, 0, 64); STAGE_A(1, 0, 64);
  asm volatile("s_waitcnt vmcnt(4)" ::: "memory");   // tile0 landed; {B0,A0}(1) in flight
  __builtin_amdgcn_s_barrier();
  asm volatile("" ::: "memory");
#pragma unroll
  for (int mi = 0; mi < 4; ++mi) {
    afp[mi][0] = *(const short8*)(smb + arB + mi * 2048 + abase);
    afp[mi][1] = *(const short8*)(smb + arB + mi * 2048 + (abase ^ 64));
  }
#pragma unroll
  for (int ni = 0; ni < 2; ++ni) {
    bfp[ni][0] = *(const short8*)(smb + brB + ni * 2048 + abase);
    bfp[ni][1] = *(const short8*)(smb + brB + ni * 2048 + (abase ^ 64));
  }

  // ---- main loop: tiles 0..63 as 32 compile-time-parity pairs ----
  // tile 2tt  (P=0): K1=(2tt+1)*64, K2=min((2tt+2)*64, 4096)
  // tile 2tt+1(P=1): K1=K2 above,   K2=min((2tt+3)*64, 4096)
  // Clamped re-stages write tile-64 data into dead regions; drained by the
  // final vmcnt(0).
  int k1 = 64, k2 = 128;
#pragma unroll 1
  for (int tt = 0; tt < 32; ++tt) {
    const int k2c = (k2 > 4096) ? 4096 : k2;
    const int k3c = (k2 + 64 > 4096) ? 4096 : k2 + 64;
    KTILE(0, k1, k2c);
    KTILE(1, k2c, k3c);
    k1 += 128; k2 += 128;
  }

  // ---- tail: tile 64 (buf0). Fully resident: tile 63's ph2-end vmcnt(2)
  // guaranteed all tile-64 halves. afp/bfp hold M0-3/N0-1 (tile 63's ph3
  // pre-read from buf0). Outstanding vmem: clamped stages into buf1 only.
  {
    short8 aft[4][2], bft[2][2];
#pragma unroll
    for (int mi = 0; mi < 4; ++mi) {
      aft[mi][0] = *(const short8*)(smb + arB + (mi + 4) * 2048 + abase);
      aft[mi][1] = *(const short8*)(smb + arB + (mi + 4) * 2048 + (abase ^ 64));
    }
#pragma unroll
    for (int ni = 0; ni < 2; ++ni) {
      bft[ni][0] = *(const short8*)(smb + brB + (ni + 2) * 2048 + abase);
      bft[ni][1] = *(const short8*)(smb + brB + (ni + 2) * 2048 + (abase ^ 64));
    }
    asm volatile("s_waitcnt lgkmcnt(0)" ::: "memory");
    __builtin_amdgcn_sched_barrier(0);
    __builtin_amdgcn_s_setprio(1);
#pragma unroll
    for (int mi = 0; mi < 4; ++mi)
#pragma unroll
      for (int ni = 0; ni < 2; ++ni) {
        MFMA2(acc[mi][ni],          afp[mi], bfp[ni]);
        MFMA2(acc[mi][ni + 2],      afp[mi], bft[ni]);
        MFMA2(acc[mi + 4][ni],      aft[mi], bfp[ni]);
        MFMA2(acc[mi + 4][ni + 2],  aft[mi], bft[ni]);
      }
    __builtin_amdgcn_s_setprio(0);
  }

  // drain stray clamped stages before LDS dealloc / block retire
  asm volatile("s_waitcnt vmcnt(0)" ::: "memory");

  // ---- epilogue: C/D layout col = r, row = q*4 + i (verified m89/m91) ----
  const int r0 = bm + wm * 128;
  const int c0 = bn + wn * 64;
#pragma unroll
  for (int mi = 0; mi < 8; ++mi)
#pragma unroll
    for (int ni = 0; ni < 4; ++ni) {
      const int row0 = r0 + mi * 16 + q * 4;
      const int col  = c0 + ni * 16 + r;
#pragma unroll
      for (int i = 0; i < 4; ++i)
        C[(size_t)(row0 + i) * N + col] = acc[mi][ni][i];
    }
}

extern "C" void kernel_launch(void* const* d_in, const int* in_sizes, int n_in,
                              void* d_out, int out_size, void* d_ws, size_t ws_size,
                              hipStream_t stream) {
  const float* a    = (const float*)d_in[0];   // [4096, 4096] fp32
  const int*   hidx = (const int*)d_in[1];     // [4096, 4097] int32
  const float* W    = (const float*)d_in[2];   // [65536] fp32
  float*       out  = (float*)d_out;           // [4096, 4096] fp32

  // workspace: A_ext bf16 [B_DIM][KP] | Wv bf16 [FAN_OUT][KP]  (68.2 MB)
  unsigned short* Ae = (unsigned short*)d_ws;
  unsigned short* Wv = Ae + (size_t)B_DIM * KP;

  static bool attr_set = false;
  if (!attr_set) {
    hipFuncSetAttribute((const void*)gemm_bt8,
                        hipFuncAttributeMaxDynamicSharedMemorySize, 131072);
    hipFuncSetAttribute((const void*)build_wv,
                        hipFuncAttributeMaxDynamicSharedMemorySize, 131072);
    attr_set = true;
  }

  build_aext<<<B_DIM, 256, 0, stream>>>(a, Ae);
  build_wv<<<FAN_OUT / 16, 1024, 131072, stream>>>(hidx, W, Wv);
  gemm_bt8<<<dim3(FAN_OUT / BN, B_DIM / BM), 512, 131072, stream>>>(Ae, Wv, out, B_DIM, FAN_OUT);
}